// Round 1
// 1414.968 us; speedup vs baseline: 1.0108x; 1.0108x over previous
//
#include <hip/hip_runtime.h>
#include <stdint.h>

// genericPINN v2: weights bypass LDS entirely (per-wave-disjoint B-frags streamed
// L2->VGPR, reg-double-buffered). LDS holds only activations (64 rows x 1KiB) + dp.
// SPB=16 -> 4096 blocks, 65 KiB LDS + <=128 VGPR -> 2 blocks/CU (16 waves).
// Barriers: 2 per layer (vs 128 per block before).

#define B_SZ   65536
#define NN     512
#define NL     8
#define SPB    16            // samples per block
#define MROWS  64            // 4 * SPB stream-rows
#define MT     4             // 64/16 M-tiles
#define NTW    4             // 16-col N-tiles per wave (8 waves * 64 cols = 512)
#define NKB    16            // K blocks per layer (512/32)
#define NG     (NL*NKB)      // 128 weight groups of 32 KiB
#define LDS_A  (MROWS*1024)  // 65536
#define LDS_TOTAL (LDS_A + 1024)   // + dp (64 rows x 16B)

typedef _Float16 f16x8 __attribute__((ext_vector_type(8)));
typedef float    f32x4 __attribute__((ext_vector_type(4)));

__device__ __forceinline__ uint16_t f2h_bits(float f) {
  union { _Float16 h; uint16_t u; } v; v.h = (_Float16)f; return v.u;
}
__device__ __forceinline__ float h2f(uint16_t b) {
  union { uint16_t u; _Float16 h; } v; v.u = b; return (float)v.h;
}

// ---- prep: Ws (L,512,512) fp32 -> f16 image laid out for direct per-wave reg loads.
// img[g][wv][Nt][lane][16B], g = l*16+kb.
// frag for lane (q=lane>>4, i16=lane&15): W[kb*32 + q*8 + e][wv*64 + Nt*16 + i16], e=0..7
__global__ __launch_bounds__(512) void prep_weights(const float* __restrict__ Ws,
                                                    uint16_t* __restrict__ img) {
  const int g  = blockIdx.x;          // 0..127
  const int l  = g >> 4, kb = g & 15;
  const float* src = Ws + ((size_t)l << 18);
  char* dst = (char*)img + ((size_t)g << 15);
  #pragma unroll
  for (int it = 0; it < 4; ++it) {
    const int fidx = threadIdx.x + it*512;          // 0..2047
    const int ln  = fidx & 63, sub = fidx >> 6;     // sub = wv*4 + Nt
    const int n     = (sub >> 2)*64 + (sub & 3)*16 + (ln & 15);
    const int kbase = kb*32 + (ln >> 4)*8;
    uint16_t h[8];
    #pragma unroll
    for (int e = 0; e < 8; ++e)
      h[e] = f2h_bits(src[(size_t)(kbase + e)*512 + n]);
    uint4 pk;
    pk.x = (uint32_t)h[0] | ((uint32_t)h[1] << 16);
    pk.y = (uint32_t)h[2] | ((uint32_t)h[3] << 16);
    pk.z = (uint32_t)h[4] | ((uint32_t)h[5] << 16);
    pk.w = (uint32_t)h[6] | ((uint32_t)h[7] << 16);
    *(uint4*)(dst + (size_t)fidx*16) = pk;
  }
}

__global__ __launch_bounds__(512, 4) void pinn_fused(
    const float* __restrict__ inputs, const float* __restrict__ Brff,
    const float* __restrict__ bs, const float* __restrict__ alphas,
    const float* __restrict__ Wf, const float* __restrict__ scl,
    const uint16_t* __restrict__ wimg, float* __restrict__ out)
{
  extern __shared__ char smem[];

  const int tid  = threadIdx.x;
  const int lane = tid & 63;
  const int wv   = tid >> 6;       // wave 0..7
  const int i16  = lane & 15;
  const int q    = lane >> 4;
  const int sbase = blockIdx.x * SPB;   // 4096 * 16 == 65536, no tail

  // ---- layer 0: u0 = [sin z, cos z]; du0_c = [cos z * B_c, -sin z * B_c] ----
  {
    const int k = tid, col = k & 255;
    const bool iscos = (k >= 256);
    const float b0 = Brff[col];
    const float b1 = Brff[256 + col];
    const float b2 = Brff[512 + col];
    const float b3 = Brff[768 + col];
    const int koff = 2*k;
    for (int s = 0; s < SPB; ++s) {
      const float4 x = *(const float4*)(inputs + ((size_t)(sbase + s) << 2));
      const float z = x.x*b0 + x.y*b1 + x.z*b2 + x.w*b3;
      const float szn = __sinf(z), czn = __cosf(z);
      const float u0 = iscos ? czn : szn;         // primal stream
      const float dz = iscos ? -szn : czn;        // d/dz chain factor
      const int m0 = 4*s;
      *(uint16_t*)(smem + (size_t)(m0+0)*1024 + (koff ^ (((m0+0) & 7)*16))) = f2h_bits(u0);
      *(uint16_t*)(smem + (size_t)(m0+1)*1024 + (koff ^ (((m0+1) & 7)*16))) = f2h_bits(dz*b1);
      *(uint16_t*)(smem + (size_t)(m0+2)*1024 + (koff ^ (((m0+2) & 7)*16))) = f2h_bits(dz*b2);
      *(uint16_t*)(smem + (size_t)(m0+3)*1024 + (koff ^ (((m0+3) & 7)*16))) = f2h_bits(dz*b3);
    }
  }
  __syncthreads();

  // per-wave weight stream base: + g*32768 + Nt*1024 below
  const char* wbase = (const char*)wimg + ((size_t)wv << 12) + (size_t)lane*16;

  f16x8 bA[NTW], bB[NTW];
  #pragma unroll
  for (int Nt = 0; Nt < NTW; ++Nt)                // preload g = 0
    bA[Nt] = *(const f16x8*)(wbase + (size_t)Nt*1024);

  f32x4 acc[MT][NTW];

  for (int l = 0; l < NL; ++l) {
    const f32x4 zz = {0.f, 0.f, 0.f, 0.f};
    #pragma unroll
    for (int a = 0; a < MT; ++a)
      #pragma unroll
      for (int b = 0; b < NTW; ++b) acc[a][b] = zz;

    #pragma unroll 1
    for (int t = 0; t < NKB/2; ++t) {
      const int g = l*NKB + 2*t;
      // prefetch g+1 -> bB (g+1 <= 127 always)
      {
        const char* p = wbase + ((size_t)(g + 1) << 15);
        #pragma unroll
        for (int Nt = 0; Nt < NTW; ++Nt) bB[Nt] = *(const f16x8*)(p + (size_t)Nt*1024);
      }
      // compute kb = 2t with bA
      {
        const int kb = 2*t;
        const int roff = (kb*64 + q*16) ^ ((i16 & 7)*16);
        #pragma unroll
        for (int Mt = 0; Mt < MT; ++Mt) {
          const f16x8 af = *(const f16x8*)(smem + (size_t)(Mt*16 + i16)*1024 + roff);
          #pragma unroll
          for (int Nt = 0; Nt < NTW; ++Nt)
            acc[Mt][Nt] = __builtin_amdgcn_mfma_f32_16x16x32_f16(af, bA[Nt], acc[Mt][Nt], 0, 0, 0);
        }
      }
      // prefetch g+2 -> bA (skipped only at the very last pair)
      if (g + 2 < NG) {
        const char* p = wbase + ((size_t)(g + 2) << 15);
        #pragma unroll
        for (int Nt = 0; Nt < NTW; ++Nt) bA[Nt] = *(const f16x8*)(p + (size_t)Nt*1024);
      }
      // compute kb = 2t+1 with bB
      {
        const int kb = 2*t + 1;
        const int roff = (kb*64 + q*16) ^ ((i16 & 7)*16);
        #pragma unroll
        for (int Mt = 0; Mt < MT; ++Mt) {
          const f16x8 af = *(const f16x8*)(smem + (size_t)(Mt*16 + i16)*1024 + roff);
          #pragma unroll
          for (int Nt = 0; Nt < NTW; ++Nt)
            acc[Mt][Nt] = __builtin_amdgcn_mfma_f32_16x16x32_f16(af, bB[Nt], acc[Mt][Nt], 0, 0, 0);
        }
      }
    }
    __syncthreads();   // all A-reads of layer l complete before overwrite

    // ---- epilogue: h=(1+a)(dot+b); u'=sin h; du'=(1+a)cos(h)*dot_t ----
    // C/D layout: col=i16 -> neuron nc, row=q*4+r -> stream-row (lane-local)
    const float opa = 1.0f + alphas[l];
    #pragma unroll
    for (int Nt = 0; Nt < NTW; ++Nt) {
      const int nc = wv*64 + Nt*16 + i16;
      const float bias = bs[l*NN + nc];
      #pragma unroll
      for (int Mt = 0; Mt < MT; ++Mt) {
        f32x4 c = acc[Mt][Nt];
        float h  = opa * (c[0] + bias);
        float un = __sinf(h);
        float fc = opa * __cosf(h);
        float vv[4] = { un, fc*c[1], fc*c[2], fc*c[3] };
        const int mb = Mt*16 + q*4;
        #pragma unroll
        for (int r = 0; r < 4; ++r) {
          const int m = mb + r;
          *(uint16_t*)(smem + (size_t)m*1024 + ((2*nc) ^ ((m & 7)*16))) = f2h_bits(vv[r]);
        }
      }
    }
    __syncthreads();
  }

  // ---- final projection: dp[m][o] = sum_k A[m][k]*Wf[k][o] * scale[o] ----
  float* dp = (float*)(smem + LDS_A);
  const float4 sc4 = *(const float4*)scl;
  for (int rr = 0; rr < MROWS/8; ++rr) {     // 8 rows per wave
    const int m = wv*(MROWS/8) + rr;
    float p0 = 0.f, p1 = 0.f, p2 = 0.f, p3 = 0.f;
    #pragma unroll
    for (int j = 0; j < 8; ++j) {
      const int k = lane + j*64;
      float a = h2f(*(const uint16_t*)(smem + (size_t)m*1024 + ((2*k) ^ ((m & 7)*16))));
      float4 wf = ((const float4*)Wf)[k];
      p0 += a*wf.x; p1 += a*wf.y; p2 += a*wf.z; p3 += a*wf.w;
    }
    #pragma unroll
    for (int d = 1; d < 64; d <<= 1) {
      p0 += __shfl_xor(p0, d, 64);
      p1 += __shfl_xor(p1, d, 64);
      p2 += __shfl_xor(p2, d, 64);
      p3 += __shfl_xor(p3, d, 64);
    }
    if (lane == 0) {
      float4* o = (float4*)(dp + m*4);
      *o = make_float4(p0*sc4.x, p1*sc4.y, p2*sc4.z, p3*sc4.w);
    }
  }
  __syncthreads();

  // rows 4s+1=dPdz, 4s+2=dPdx, 4s+3=dPdy
  // u = dPdy[2]-dPdz[1]+dPdx[3]; v = dPdz[0]-dPdx[2]+dPdy[3]; w = dPdx[1]-dPdy[0]+dPdz[3]
  if (tid < SPB*3) {
    const int sl = tid / 3, c = tid - sl*3;
    const float* d1 = dp + (sl*4 + 1)*4;
    const float* d2 = dp + (sl*4 + 2)*4;
    const float* d3 = dp + (sl*4 + 3)*4;
    float val;
    if (c == 0)      val = d3[2] - d1[1] + d2[3];
    else if (c == 1) val = d1[0] - d2[2] + d3[3];
    else             val = d2[1] - d3[0] + d1[3];
    out[(size_t)(sbase + sl)*3 + c] = val;
  }
}

extern "C" void kernel_launch(void* const* d_in, const int* in_sizes, int n_in,
                              void* d_out, int out_size, void* d_ws, size_t ws_size,
                              hipStream_t stream) {
  const float* inputs = (const float*)d_in[0];
  const float* Brff   = (const float*)d_in[1];
  const float* Ws     = (const float*)d_in[2];
  const float* bsp    = (const float*)d_in[3];
  const float* alph   = (const float*)d_in[4];
  const float* Wfp    = (const float*)d_in[5];
  const float* sclp   = (const float*)d_in[6];
  uint16_t* wimg = (uint16_t*)d_ws;           // needs 4 MiB workspace

  prep_weights<<<NG, 512, 0, stream>>>(Ws, wimg);
  const int nblocks = B_SZ / SPB;             // 4096
  pinn_fused<<<nblocks, 512, LDS_TOTAL, stream>>>(inputs, Brff, bsp, alph, Wfp, sclp,
                                                  wimg, (float*)d_out);
}

// Round 2
// 1342.578 us; speedup vs baseline: 1.0653x; 1.0539x over previous
//
#include <hip/hip_runtime.h>
#include <stdint.h>

// genericPINN v3: 32x32x16 f16 MFMA + full register double-buffering of A (LDS) and
// B (global) fragments with prefetch-before-compute ordering to break phase convoy.
// 8 waves: each computes all 64 stream-rows x its 64 cols (2x2 tiles of 32x32).
// LDS = activations only (64 x 1KiB swizzled) + dp. 2 blocks/CU (16 waves).

#define B_SZ   65536
#define NN     512
#define NL     8
#define SPB    16            // samples per block
#define MROWS  64            // 4 * SPB stream-rows
#define NKS    32            // K-steps of 16 per layer (512/16)
#define NG2    (NL*NKS)      // 256 weight groups of 16 KiB
#define LDS_A  (MROWS*1024)  // 65536
#define LDS_TOTAL (LDS_A + 1024)

typedef _Float16 f16x8  __attribute__((ext_vector_type(8)));
typedef float    f32x16 __attribute__((ext_vector_type(16)));

__device__ __forceinline__ uint16_t f2h_bits(float f) {
  union { _Float16 h; uint16_t u; } v; v.h = (_Float16)f; return v.u;
}
__device__ __forceinline__ float h2f(uint16_t b) {
  union { uint16_t u; _Float16 h; } v; v.u = b; return (float)v.h;
}

// ---- prep: Ws (L,512,512) fp32 -> f16 image for per-wave 32x32x16 B-frag reg loads.
// img[g2][wv][Nt][lane][16B], g2 = l*32 + ks  (16 KiB per group).
// frag for lane: W[ks*16 + (lane>>5)*8 + e][wv*64 + Nt*32 + (lane&31)], e=0..7
__global__ __launch_bounds__(512) void prep_weights(const float* __restrict__ Ws,
                                                    uint16_t* __restrict__ img) {
  const int g2 = blockIdx.x;              // 0..255
  const int l  = g2 >> 5, ks = g2 & 31;
  const float* src = Ws + ((size_t)l << 18);
  char* dst = (char*)img + ((size_t)g2 << 14);
  #pragma unroll
  for (int it = 0; it < 2; ++it) {
    const int fidx = threadIdx.x + it*512;          // 0..1023 fragments
    const int ln  = fidx & 63, sub = fidx >> 6;     // sub = wv*2 + Nt
    const int n     = (sub >> 1)*64 + (sub & 1)*32 + (ln & 31);
    const int kbase = ks*16 + (ln >> 5)*8;
    uint16_t h[8];
    #pragma unroll
    for (int e = 0; e < 8; ++e)
      h[e] = f2h_bits(src[(size_t)(kbase + e)*512 + n]);
    uint4 pk;
    pk.x = (uint32_t)h[0] | ((uint32_t)h[1] << 16);
    pk.y = (uint32_t)h[2] | ((uint32_t)h[3] << 16);
    pk.z = (uint32_t)h[4] | ((uint32_t)h[5] << 16);
    pk.w = (uint32_t)h[6] | ((uint32_t)h[7] << 16);
    *(uint4*)(dst + (size_t)fidx*16) = pk;
  }
}

__global__ __launch_bounds__(512, 4) void pinn_fused(
    const float* __restrict__ inputs, const float* __restrict__ Brff,
    const float* __restrict__ bs, const float* __restrict__ alphas,
    const float* __restrict__ Wf, const float* __restrict__ scl,
    const uint16_t* __restrict__ wimg, float* __restrict__ out)
{
  extern __shared__ char smem[];

  const int tid  = threadIdx.x;
  const int lane = tid & 63;
  const int wv   = tid >> 6;        // wave 0..7
  const int l31  = lane & 31;
  const int kh   = lane >> 5;       // k-half (0/1)
  const int sbase = blockIdx.x * SPB;   // 4096 * 16 == 65536

  // per-wave weight stream base: + g2*16384 + Nt*1024 below
  const char* wb = (const char*)wimg + ((size_t)(wv*2) << 10) + (size_t)lane*16;

  // issue B prefetch for g2 = 0,1 immediately (independent of layer 0)
  f16x8 bfA0 = *(const f16x8*)(wb);
  f16x8 bfA1 = *(const f16x8*)(wb + 1024);
  f16x8 bfB0 = *(const f16x8*)(wb + 16384);
  f16x8 bfB1 = *(const f16x8*)(wb + 16384 + 1024);

  // ---- layer 0: u0 = [sin z, cos z]; du0_c = [cos z * B_c, -sin z * B_c] ----
  {
    const int k = tid, col = k & 255;
    const bool iscos = (k >= 256);
    const float b0 = Brff[col];
    const float b1 = Brff[256 + col];
    const float b2 = Brff[512 + col];
    const float b3 = Brff[768 + col];
    const int koff = 2*k;
    for (int s = 0; s < SPB; ++s) {
      const float4 x = *(const float4*)(inputs + ((size_t)(sbase + s) << 2));
      const float z = x.x*b0 + x.y*b1 + x.z*b2 + x.w*b3;
      const float szn = __sinf(z), czn = __cosf(z);
      const float u0 = iscos ? czn : szn;
      const float dz = iscos ? -szn : czn;
      const int m0 = 4*s;
      *(uint16_t*)(smem + (size_t)(m0+0)*1024 + (koff ^ (((m0+0) & 7)*16))) = f2h_bits(u0);
      *(uint16_t*)(smem + (size_t)(m0+1)*1024 + (koff ^ (((m0+1) & 7)*16))) = f2h_bits(dz*b1);
      *(uint16_t*)(smem + (size_t)(m0+2)*1024 + (koff ^ (((m0+2) & 7)*16))) = f2h_bits(dz*b2);
      *(uint16_t*)(smem + (size_t)(m0+3)*1024 + (koff ^ (((m0+3) & 7)*16))) = f2h_bits(dz*b3);
    }
  }
  __syncthreads();

  // ---- A-frag addressing (rows m = Mt*32 + l31, k-chunk byte col = ks*32 + kh*16) ----
  const int rx   = (l31 & 7) * 16;       // row swizzle (Mt*32 doesn't change m&7)
  const int hoff = kh * 16;
  char* arow0 = smem + (size_t)l31 * 1024;
  char* arow1 = arow0 + 32*1024;

  f16x8 afA0 = *(const f16x8*)(arow0 + (hoff ^ rx));   // ks = 0
  f16x8 afA1 = *(const f16x8*)(arow1 + (hoff ^ rx));
  f16x8 afB0, afB1;

  const f32x16 zz = {0,0,0,0,0,0,0,0,0,0,0,0,0,0,0,0};

  for (int l = 0; l < NL; ++l) {
    f32x16 a00 = zz, a01 = zz, a10 = zz, a11 = zz;
    const int g2b = l*NKS;

    #pragma unroll 1
    for (int t = 0; t < NKS/2; ++t) {
      const int ks = 2*t;
      // prefetch af(ks+1) -> afB (before the MFMA cluster; ks+1 <= 31 always)
      {
        const int co = ((ks + 1)*32 + hoff) ^ rx;
        afB0 = *(const f16x8*)(arow0 + co);
        afB1 = *(const f16x8*)(arow1 + co);
      }
      __builtin_amdgcn_s_setprio(1);
      a00 = __builtin_amdgcn_mfma_f32_32x32x16_f16(afA0, bfA0, a00, 0, 0, 0);
      a01 = __builtin_amdgcn_mfma_f32_32x32x16_f16(afA0, bfA1, a01, 0, 0, 0);
      a10 = __builtin_amdgcn_mfma_f32_32x32x16_f16(afA1, bfA0, a10, 0, 0, 0);
      a11 = __builtin_amdgcn_mfma_f32_32x32x16_f16(afA1, bfA1, a11, 0, 0, 0);
      __builtin_amdgcn_s_setprio(0);
      // reload bfA for ks+2 (2-kstep load-to-use distance)
      {
        const int gt = g2b + ks + 2;
        if (gt < NG2) {
          const char* p = wb + ((size_t)gt << 14);
          bfA0 = *(const f16x8*)(p);
          bfA1 = *(const f16x8*)(p + 1024);
        }
      }
      // prefetch af(ks+2) -> afA (skip at layer tail)
      if (t + 1 < NKS/2) {
        const int co = ((ks + 2)*32 + hoff) ^ rx;
        afA0 = *(const f16x8*)(arow0 + co);
        afA1 = *(const f16x8*)(arow1 + co);
      }
      __builtin_amdgcn_s_setprio(1);
      a00 = __builtin_amdgcn_mfma_f32_32x32x16_f16(afB0, bfB0, a00, 0, 0, 0);
      a01 = __builtin_amdgcn_mfma_f32_32x32x16_f16(afB0, bfB1, a01, 0, 0, 0);
      a10 = __builtin_amdgcn_mfma_f32_32x32x16_f16(afB1, bfB0, a10, 0, 0, 0);
      a11 = __builtin_amdgcn_mfma_f32_32x32x16_f16(afB1, bfB1, a11, 0, 0, 0);
      __builtin_amdgcn_s_setprio(0);
      {
        const int gt = g2b + ks + 3;
        if (gt < NG2) {
          const char* p = wb + ((size_t)gt << 14);
          bfB0 = *(const f16x8*)(p);
          bfB1 = *(const f16x8*)(p + 1024);
        }
      }
    }
    __syncthreads();   // all A-reads of layer l complete before overwrite

    // ---- epilogue: h=(1+a)(dot+b); u'=sin h; du'=(1+a)cos(h)*dot_t ----
    // 32x32 C/D layout: col = lane&31, row = (r&3) + 8*(r>>2) + 4*(lane>>5)
    // -> reg group r=4j..4j+3 holds the 4 streams (s = r&3) of row 8j+4*kh
    const float opa = 1.0f + alphas[l];
    #pragma unroll
    for (int Nt = 0; Nt < 2; ++Nt) {
      const int nc = wv*64 + Nt*32 + l31;
      const float bias = bs[l*NN + nc];
      #pragma unroll
      for (int Mt = 0; Mt < 2; ++Mt) {
        const f32x16 c = (Mt == 0) ? (Nt == 0 ? a00 : a01)
                                   : (Nt == 0 ? a10 : a11);
        #pragma unroll
        for (int j = 0; j < 4; ++j) {
          const float hh = opa * (c[4*j] + bias);
          const float un = __sinf(hh);
          const float fc = opa * __cosf(hh);
          const float vv[4] = { un, fc*c[4*j+1], fc*c[4*j+2], fc*c[4*j+3] };
          const int m0 = Mt*32 + 8*j + 4*kh;
          #pragma unroll
          for (int s = 0; s < 4; ++s) {
            const int m = m0 + s;
            *(uint16_t*)(smem + (size_t)m*1024 + ((2*nc) ^ ((m & 7)*16))) = f2h_bits(vv[s]);
          }
        }
      }
    }
    __syncthreads();

    if (l + 1 < NL) {   // preload ks=0 of next layer
      afA0 = *(const f16x8*)(arow0 + (hoff ^ rx));
      afA1 = *(const f16x8*)(arow1 + (hoff ^ rx));
    }
  }

  // ---- final projection: dp[m][o] = sum_k A[m][k]*Wf[k][o] * scale[o] ----
  float* dp = (float*)(smem + LDS_A);
  const float4 sc4 = *(const float4*)scl;
  for (int rr = 0; rr < MROWS/8; ++rr) {     // 8 rows per wave
    const int m = wv*(MROWS/8) + rr;
    float p0 = 0.f, p1 = 0.f, p2 = 0.f, p3 = 0.f;
    #pragma unroll
    for (int j = 0; j < 8; ++j) {
      const int k = lane + j*64;
      float a = h2f(*(const uint16_t*)(smem + (size_t)m*1024 + ((2*k) ^ ((m & 7)*16))));
      float4 wf = ((const float4*)Wf)[k];
      p0 += a*wf.x; p1 += a*wf.y; p2 += a*wf.z; p3 += a*wf.w;
    }
    #pragma unroll
    for (int d = 1; d < 64; d <<= 1) {
      p0 += __shfl_xor(p0, d, 64);
      p1 += __shfl_xor(p1, d, 64);
      p2 += __shfl_xor(p2, d, 64);
      p3 += __shfl_xor(p3, d, 64);
    }
    if (lane == 0) {
      float4* o = (float4*)(dp + m*4);
      *o = make_float4(p0*sc4.x, p1*sc4.y, p2*sc4.z, p3*sc4.w);
    }
  }
  __syncthreads();

  // rows 4s+1=dPdz, 4s+2=dPdx, 4s+3=dPdy
  // u = dPdy[2]-dPdz[1]+dPdx[3]; v = dPdz[0]-dPdx[2]+dPdy[3]; w = dPdx[1]-dPdy[0]+dPdz[3]
  if (tid < SPB*3) {
    const int sl = tid / 3, c = tid - sl*3;
    const float* d1 = dp + (sl*4 + 1)*4;
    const float* d2 = dp + (sl*4 + 2)*4;
    const float* d3 = dp + (sl*4 + 3)*4;
    float val;
    if (c == 0)      val = d3[2] - d1[1] + d2[3];
    else if (c == 1) val = d1[0] - d2[2] + d3[3];
    else             val = d2[1] - d3[0] + d1[3];
    out[(size_t)(sbase + sl)*3 + c] = val;
  }
}

extern "C" void kernel_launch(void* const* d_in, const int* in_sizes, int n_in,
                              void* d_out, int out_size, void* d_ws, size_t ws_size,
                              hipStream_t stream) {
  const float* inputs = (const float*)d_in[0];
  const float* Brff   = (const float*)d_in[1];
  const float* Ws     = (const float*)d_in[2];
  const float* bsp    = (const float*)d_in[3];
  const float* alph   = (const float*)d_in[4];
  const float* Wfp    = (const float*)d_in[5];
  const float* sclp   = (const float*)d_in[6];
  uint16_t* wimg = (uint16_t*)d_ws;           // needs 4 MiB workspace

  prep_weights<<<NG2, 512, 0, stream>>>(Ws, wimg);
  const int nblocks = B_SZ / SPB;             // 4096
  pinn_fused<<<nblocks, 512, LDS_TOTAL, stream>>>(inputs, Brff, bsp, alph, Wfp, sclp,
                                                  wimg, (float*)d_out);
}